// Round 8
// baseline (184.374 us; speedup 1.0000x reference)
//
#include <hip/hip_runtime.h>

// Chamfer loss, B=8, N=M=8192, D=3, fp32 I/O — MFMA R9: no-LDS register-direct.
//
// R8 post-mortem: counted-vmcnt ring didn't move pass1 (43us) — limiter is
// not sync-drain but shared-pipe volume: every wave ds_reads every tile
// (4x redundant, 1536 cyc/CU/round LDS) + 1184 cyc/SIMD VALU fold, in
// ~300cyc barrier lockstep. Per guide Common-mistake #7: the hot b-image
// is ~1MB/XCD = L2-RESIDENT -> staging it through LDS is pure overhead.
//
// R9: each wave loads b-fragments DIRECTLY from global (1KB/wave
// coalesced global_load_dwordx4, L1/L2-served). No LDS, no DMA, no
// waitcnt asm, no barriers in the main loop (one raw s_barrier per
// 16-tile group keeps the 4 waves' windows L1-co-resident). Freed
// registers -> F=4 named a-frag chains (spill history: arrays+staging
// spilled; named scalars at 32-52 VGPR never did), halving b-traffic
// per pair: 262MB total cache reads ~ 7.6us at L2 ceiling; VALU fold
// (~20k cyc/SIMD) becomes the binding pipe ~ 8.3us.
//   - A_blk=512 (wave = 4 frags x 32 a-pts), NCH4=4 -> 1024 blocks,
//     launch_bounds(256,4) = 4 blocks/CU, VGPR cap 128 (est ~70-100).
//   - unchanged: pass0 fmt image, bijective XCD swizzle (1024=8*128),
//     pass2fin float4 + atomic last-block finish.
//
//   v_mfma_f32_32x32x16_f16, K-slots (13/16), coords pre-scaled x16:
//     b (A-op): k0-7 = bh_x bh_y bh_z bl_x bl_y bl_z bh_x bh_y
//               k8-15 = bh_z ch cl 1 1 0 0 0          (c = -0.5|b|^2 split)
//     a (B-op): k0-7 = ah_x ah_y ah_z ah_x ah_y ah_z al_x al_y
//               k8-15 = al_z 1 1 dh dl 0 0 0          (d = -0.5|a|^2 split)
//   => v = -d2/2 (scaled 256); d2 = max_b(v) * (-1/128), clamp 0.

#define BATCH   8
#define NPTS    8192
#define BLK     256
#define TOTAL_A (2 * BATCH * NPTS)            // 131072
#define NCH4    4                             // b-quarters
#define BQUART  (NPTS / NCH4)                 // 2048
#define NTILES  (BQUART / 32)                 // 64 b-tiles per block
#define ABLK_SZ 512                           // a-points per block
#define ABLKS   (NPTS / ABLK_SZ)              // 16 per (side,batch)
#define P1_BLOCKS (2 * BATCH * ABLKS * NCH4)  // 1024
#define P2_BLOCKS (TOTAL_A / BLK)             // 512
#define SC      16.0f                         // exact pow2 coord scale

typedef _Float16 f16x8  __attribute__((ext_vector_type(8)));
typedef float    f32x16 __attribute__((ext_vector_type(16)));

static __device__ __forceinline__ unsigned int pk2(float a, float b) {
  unsigned short ua = __builtin_bit_cast(unsigned short, (_Float16)a);
  unsigned short ub = __builtin_bit_cast(unsigned short, (_Float16)b);
  return (unsigned int)ua | ((unsigned int)ub << 16);
}

// 16 accumulator values + running max -> 8 v_max3_f32
static __device__ __forceinline__ float fold16(float mq, f32x16 d) {
  float t0 = fmaxf(fmaxf(d[0],  d[1]),  d[2]);
  float t1 = fmaxf(fmaxf(d[3],  d[4]),  d[5]);
  float t2 = fmaxf(fmaxf(d[6],  d[7]),  d[8]);
  float t3 = fmaxf(fmaxf(d[9],  d[10]), d[11]);
  float t4 = fmaxf(fmaxf(d[12], d[13]), d[14]);
  float t5 = fmaxf(fmaxf(t0, t1), t2);
  float t6 = fmaxf(fmaxf(t3, t4), d[15]);
  return fmaxf(fmaxf(mq, t5), t6);
}

// b-point -> A-operand fragment pair (byte-identical to R3..R8)
static __device__ __forceinline__ void fmt_point(float X, float Y, float Z,
                                                 uint4* lo, uint4* hi) {
  float x = X * SC, y = Y * SC, z = Z * SC;
  float fx = (float)(_Float16)x, fy = (float)(_Float16)y, fz = (float)(_Float16)z;
  float lx = x - fx, ly = y - fy, lz = z - fz;
  float b2 = fmaf(x, x, fmaf(y, y, z * z));
  float c  = -0.5f * b2;
  float fc = (float)(_Float16)c;
  float lc = c - fc;
  *lo = make_uint4(pk2(x, y), pk2(z, lx), pk2(ly, lz), pk2(x, y));
  *hi = make_uint4(pk2(z, c), pk2(lc, 1.0f), 0x00003C00u, 0u);
}

// a-point -> B-operand fragment (col = lane&31, k-group = lane>>5)
static __device__ __forceinline__ f16x8 make_afrag(float X, float Y, float Z,
                                                   int hi) {
  float x = X * SC, y = Y * SC, z = Z * SC;
  float fx = (float)(_Float16)x, fy = (float)(_Float16)y, fz = (float)(_Float16)z;
  float lx = x - fx, ly = y - fy, lz = z - fz;
  float a2 = fmaf(x, x, fmaf(y, y, z * z));
  float dd = -0.5f * a2;
  float fd = (float)(_Float16)dd;
  float ld = dd - fd;
  uint4 u;
  if (!hi) {
    u = make_uint4(pk2(x, y), pk2(z, x), pk2(y, z), pk2(lx, ly));
  } else {
    u = make_uint4(pk2(lz, 1.0f), pk2(1.0f, dd), pk2(ld, 0.0f), 0u);
  }
  return __builtin_bit_cast(f16x8, u);
}

// pass0: format every point. Region = arr*8+batch (16384 uint4):
//   pt p: lo at region*16384 + (p>>5)*64 + (p&31), hi at +32.
__global__ __launch_bounds__(BLK) void chamfer_fmt(
    const float* __restrict__ pred, const float* __restrict__ gt,
    uint4* __restrict__ fmt, unsigned int* __restrict__ counter) {
  const int gid = blockIdx.x * BLK + threadIdx.x;   // [0, TOTAL_A)
  if (gid == 0) *counter = 0u;                      // reset for pass2fin
  const int arr = gid >> 16;                        // 0=pred, 1=gt
  const int idx = gid & 65535;
  const float* src = arr ? gt : pred;
  float X = src[(size_t)idx * 3 + 0];
  float Y = src[(size_t)idx * 3 + 1];
  float Z = src[(size_t)idx * 3 + 2];
  uint4 lo, hi;
  fmt_point(X, Y, Z, &lo, &hi);
  const int region = gid >> 13;
  const int p      = gid & 8191;
  size_t base = (size_t)region * 16384 + (size_t)(p >> 5) * 64 + (p & 31);
  fmt[base]      = lo;
  fmt[base + 32] = hi;
}

__global__ __launch_bounds__(BLK, 4) void chamfer_mfma_pass1(
    const float* __restrict__ pred, const float* __restrict__ gt,
    const uint4* __restrict__ fmt, float* __restrict__ partial) {
  // bijective XCD swizzle (1024 = 8 * 128)
  const int swz   = ((blockIdx.x & 7) << 7) | (blockIdx.x >> 3);
  const int qc    = swz & 3;            // b-quarter
  const int r     = swz >> 2;           // [0,256)
  const int ablk  = r & (ABLKS - 1);    // 16 a-blocks of 512
  const int bd    = r >> 4;             // side*8 + batch
  const int batch = bd & 7;
  const int side  = bd >> 3;

  const float* A    = side ? gt : pred;
  const uint4* fmtB = fmt + (size_t)((1 - side) * 8 + batch) * 16384
                          + (size_t)qc * 4096;   // 64 tiles of 64 uint4

  const int t    = threadIdx.x;
  const int lane = t & 63;
  const int wave = t >> 6;
  const int col  = lane & 31;
  const int hi   = lane >> 5;

  // 4 named a-frag chains (F=4): wave covers a-pts [wave*128, +128)
  const float* Ab = A + ((size_t)batch * NPTS + (size_t)ablk * ABLK_SZ
                         + (size_t)wave * 128) * 3;
  f16x8 af0 = make_afrag(Ab[(0 * 32 + col) * 3 + 0], Ab[(0 * 32 + col) * 3 + 1],
                         Ab[(0 * 32 + col) * 3 + 2], hi);
  f16x8 af1 = make_afrag(Ab[(1 * 32 + col) * 3 + 0], Ab[(1 * 32 + col) * 3 + 1],
                         Ab[(1 * 32 + col) * 3 + 2], hi);
  f16x8 af2 = make_afrag(Ab[(2 * 32 + col) * 3 + 0], Ab[(2 * 32 + col) * 3 + 1],
                         Ab[(2 * 32 + col) * 3 + 2], hi);
  f16x8 af3 = make_afrag(Ab[(3 * 32 + col) * 3 + 0], Ab[(3 * 32 + col) * 3 + 1],
                         Ab[(3 * 32 + col) * 3 + 2], hi);
  float mq0 = -3.0e38f, mq1 = -3.0e38f, mq2 = -3.0e38f, mq3 = -3.0e38f;
  const f32x16 zero = {};

  const uint4* bp = fmtB + lane;   // lane's 16B within each 1KB tile

  // main loop: 64 tiles, direct global->reg b-fragments (L1/L2-served;
  // hot set ~1MB/XCD). Raw s_barrier per 16-tile group bounds wave
  // drift so the block's 4 waves share L1 lines. No other sync.
  for (int g = 0; g < 4; ++g) {
#pragma unroll 4
    for (int tt = g * 16; tt < g * 16 + 16; ++tt) {
      f16x8 bf = *(const f16x8*)(bp + (size_t)tt * 64);
      f32x16 d0 = __builtin_amdgcn_mfma_f32_32x32x16_f16(bf, af0, zero, 0, 0, 0);
      mq0 = fold16(mq0, d0);
      f32x16 d1 = __builtin_amdgcn_mfma_f32_32x32x16_f16(bf, af1, zero, 0, 0, 0);
      mq1 = fold16(mq1, d1);
      f32x16 d2 = __builtin_amdgcn_mfma_f32_32x32x16_f16(bf, af2, zero, 0, 0, 0);
      mq2 = fold16(mq2, d2);
      f32x16 d3 = __builtin_amdgcn_mfma_f32_32x32x16_f16(bf, af3, zero, 0, 0, 0);
      mq3 = fold16(mq3, d3);
    }
    if (g < 3) __builtin_amdgcn_s_barrier();
  }

  // lanes l, l+32: disjoint b-rows of the same a-col
  mq0 = fmaxf(mq0, __shfl_xor(mq0, 32));
  mq1 = fmaxf(mq1, __shfl_xor(mq1, 32));
  mq2 = fmaxf(mq2, __shfl_xor(mq2, 32));
  mq3 = fmaxf(mq3, __shfl_xor(mq3, 32));

  if (lane < 32) {
    size_t a0 = (size_t)bd * NPTS + (size_t)ablk * ABLK_SZ
              + (size_t)wave * 128 + col;
    partial[(a0 + 0)  * NCH4 + qc] = mq0;
    partial[(a0 + 32) * NCH4 + qc] = mq1;
    partial[(a0 + 64) * NCH4 + qc] = mq2;
    partial[(a0 + 96) * NCH4 + qc] = mq3;
  }
}

__global__ __launch_bounds__(BLK) void chamfer_pass2fin(
    const float4* __restrict__ partial, float* __restrict__ blockSums,
    unsigned int* __restrict__ counter, float* __restrict__ out) {
  __shared__ float wsum[BLK / 64];
  __shared__ int amLast;

  const int gid = blockIdx.x * BLK + threadIdx.x;   // [0, TOTAL_A)
  float4 p = partial[gid];
  float m  = fmaxf(fmaxf(p.x, p.y), fmaxf(p.z, p.w));
  // v = -d2_scaled/2, scale = 256  =>  d2 = m * (-1/128), clamp 0
  float d2 = fmaxf(m * (-1.0f / 128.0f), 0.0f);

  const int lane = threadIdx.x & 63, wave = threadIdx.x >> 6;
  float v = d2;
  for (int off = 32; off > 0; off >>= 1) v += __shfl_down(v, off);
  if (lane == 0) wsum[wave] = v;
  __syncthreads();
  if (threadIdx.x == 0) {
    float s = (wsum[0] + wsum[1]) + (wsum[2] + wsum[3]);
    blockSums[blockIdx.x] = s;
    __threadfence();
    unsigned int prev = atomicAdd(counter, 1u);
    amLast = (prev == P2_BLOCKS - 1);
  }
  __syncthreads();

  // deterministic final reduce by the last block
  if (amLast) {
    __threadfence();
    const volatile float* vbs = blockSums;
    float v2 = vbs[threadIdx.x] + vbs[threadIdx.x + 256];
    for (int off = 32; off > 0; off >>= 1) v2 += __shfl_down(v2, off);
    if (lane == 0) wsum[wave] = v2;
    __syncthreads();
    if (threadIdx.x == 0) {
      float s = ((wsum[0] + wsum[1]) + wsum[2]) + wsum[3];
      out[0] = s * (1.0f / (float)TOTAL_A);   // (sum1+sum2)/(2*65536)
    }
  }
}

extern "C" void kernel_launch(void* const* d_in, const int* in_sizes, int n_in,
                              void* d_out, int out_size, void* d_ws, size_t ws_size,
                              hipStream_t stream) {
  const float* pred = (const float*)d_in[0];
  const float* gt   = (const float*)d_in[1];
  float* out = (float*)d_out;

  uint4*        fmtb      = (uint4*)d_ws;                                  // 4 MB
  float*        partial   = (float*)((char*)d_ws + (size_t)TOTAL_A * 32);  // 2 MB
  float*        blockSums = partial + (size_t)TOTAL_A * NCH4;
  unsigned int* counter   = (unsigned int*)(blockSums + P2_BLOCKS);

  chamfer_fmt<<<TOTAL_A / BLK, BLK, 0, stream>>>(pred, gt, fmtb, counter);
  chamfer_mfma_pass1<<<P1_BLOCKS, BLK, 0, stream>>>(pred, gt, fmtb, partial);
  chamfer_pass2fin<<<P2_BLOCKS, BLK, 0, stream>>>((const float4*)partial,
                                                  blockSums, counter, out);
}

// Round 10
// 105.727 us; speedup vs baseline: 1.7439x; 1.7439x over previous
//
#include <hip/hip_runtime.h>

// Chamfer loss, B=8, N=M=8192, D=3, fp32 I/O — MFMA R11: correct VGPR-dest asm.
//
// R10 post-mortem (absmax 1.3e-2): raw "=v" asm MFMA broke two rules:
// (a) no early-clobber -> d could alias a/b/zero (clobbering the shared
// C-block), (b) CDNA needs ~18 SW wait-states between a 16-pass MFMA
// VGPR write and a VALU read of it; the compiler inserts s_nops for
// intrinsics but cannot see into inline asm.
//
// The motive stands, now quantified: at R8's 8 waves/SIMD the unified
// RF budget is 64 regs/wave (VGPR_Count 32 + 32 AGPR acc = 64), so each
// fold16 drains AGPRs via 16x v_accvgpr_read: modeled VALU 16.4k(fold)
// +32.8k(reads) = 49k cyc/SIMD ~= measured 41k (VALUBusy 40%).
//
// R11 = R8 (last fully-passing kernel, 42.9us) + three changes:
//   1. mfma_v: "=&v" early-clobber + s_nop 7/7/2 INSIDE the asm (19
//      wait-states >= 16-pass hazard) -> correct regardless of compiler
//      scheduling; other waves fill the bubbles.
//   2. launch_bounds(256,4): 128-reg budget, d0+d1+zero+af+bf ~= 74
//      VGPRs -> no AGPRs, no spill, 4 waves/SIMD.
//   3. nothing else: values bitwise identical to R8 (absmax must be 0).
// New pipe model: VALU 16.4k cyc/SIMD, LDS 24.6k cyc/CU (binder),
// MFMA 8.2k -> pass1 floor ~10us.
//
//   v_mfma_f32_32x32x16_f16, K-slots (13/16), coords pre-scaled x16:
//     b (A-op): k0-7 = bh_x bh_y bh_z bl_x bl_y bl_z bh_x bh_y
//               k8-15 = bh_z ch cl 1 1 0 0 0          (c = -0.5|b|^2 split)
//     a (B-op): k0-7 = ah_x ah_y ah_z ah_x ah_y ah_z al_x al_y
//               k8-15 = al_z 1 1 dh dl 0 0 0          (d = -0.5|a|^2 split)
//   => v = -d2/2 (scaled 256); d2 = max_b(v) * (-1/128), clamp 0.

#define BATCH   8
#define NPTS    8192
#define BLK     256
#define TOTAL_A (2 * BATCH * NPTS)            // 131072
#define NCH4    4                             // b-quarters
#define BQUART  (NPTS / NCH4)                 // 2048
#define CHUNK   128                           // staged b-points per round
#define NCHUNK  (BQUART / CHUNK)              // 16
#define TPC     (CHUNK / 32)                  // 4 tiles per chunk
#define CU4     (CHUNK * 2)                   // 256 uint4 per chunk (4KB)
#define NBUF    4
#define ABLKS   (NPTS / 256)                  // 32
#define P1_BLOCKS (2 * BATCH * ABLKS * NCH4)  // 2048
#define P2_BLOCKS (TOTAL_A / BLK)             // 512
#define SC      16.0f                         // exact pow2 coord scale

typedef _Float16 f16x8  __attribute__((ext_vector_type(8)));
typedef float    f32x16 __attribute__((ext_vector_type(16)));
typedef __attribute__((address_space(1))) const void gptr_t;
typedef __attribute__((address_space(3))) void lptr_t;

// MFMA with VGPR-pinned destination. "=&v": d never aliases a/b/c.
// Trailing s_nops (19 wait-states) cover the 16-pass MFMA->VALU-read
// hazard entirely inside the block: by the time any later instruction
// runs, the MFMA has retired. Other resident waves fill the bubble.
static __device__ __forceinline__ f32x16 mfma_v(f16x8 a, f16x8 b,
                                                const f32x16& c) {
  f32x16 d;
  asm("v_mfma_f32_32x32x16_f16 %0, %1, %2, %3\n\t"
      "s_nop 7\n\t"
      "s_nop 7\n\t"
      "s_nop 2"
      : "=&v"(d) : "v"(a), "v"(b), "v"(c));
  return d;
}

static __device__ __forceinline__ unsigned int pk2(float a, float b) {
  unsigned short ua = __builtin_bit_cast(unsigned short, (_Float16)a);
  unsigned short ub = __builtin_bit_cast(unsigned short, (_Float16)b);
  return (unsigned int)ua | ((unsigned int)ub << 16);
}

// 16 accumulator values + running max -> 8 v_max3_f32 (on VGPRs now)
static __device__ __forceinline__ float fold16(float mq, f32x16 d) {
  float t0 = fmaxf(fmaxf(d[0],  d[1]),  d[2]);
  float t1 = fmaxf(fmaxf(d[3],  d[4]),  d[5]);
  float t2 = fmaxf(fmaxf(d[6],  d[7]),  d[8]);
  float t3 = fmaxf(fmaxf(d[9],  d[10]), d[11]);
  float t4 = fmaxf(fmaxf(d[12], d[13]), d[14]);
  float t5 = fmaxf(fmaxf(t0, t1), t2);
  float t6 = fmaxf(fmaxf(t3, t4), d[15]);
  return fmaxf(fmaxf(mq, t5), t6);
}

// b-point -> A-operand fragment pair (byte-identical to R3..R8)
static __device__ __forceinline__ void fmt_point(float X, float Y, float Z,
                                                 uint4* lo, uint4* hi) {
  float x = X * SC, y = Y * SC, z = Z * SC;
  float fx = (float)(_Float16)x, fy = (float)(_Float16)y, fz = (float)(_Float16)z;
  float lx = x - fx, ly = y - fy, lz = z - fz;
  float b2 = fmaf(x, x, fmaf(y, y, z * z));
  float c  = -0.5f * b2;
  float fc = (float)(_Float16)c;
  float lc = c - fc;
  *lo = make_uint4(pk2(x, y), pk2(z, lx), pk2(ly, lz), pk2(x, y));
  *hi = make_uint4(pk2(z, c), pk2(lc, 1.0f), 0x00003C00u, 0u);
}

// a-point -> B-operand fragment (col = lane&31, k-group = lane>>5)
static __device__ __forceinline__ f16x8 make_afrag(float X, float Y, float Z,
                                                   int hi) {
  float x = X * SC, y = Y * SC, z = Z * SC;
  float fx = (float)(_Float16)x, fy = (float)(_Float16)y, fz = (float)(_Float16)z;
  float lx = x - fx, ly = y - fy, lz = z - fz;
  float a2 = fmaf(x, x, fmaf(y, y, z * z));
  float dd = -0.5f * a2;
  float fd = (float)(_Float16)dd;
  float ld = dd - fd;
  uint4 u;
  if (!hi) {
    u = make_uint4(pk2(x, y), pk2(z, x), pk2(y, z), pk2(lx, ly));
  } else {
    u = make_uint4(pk2(lz, 1.0f), pk2(1.0f, dd), pk2(ld, 0.0f), 0u);
  }
  return __builtin_bit_cast(f16x8, u);
}

// pass0: format every point. Region = arr*8+batch (16384 uint4):
//   pt p: lo at region*16384 + (p>>5)*64 + (p&31), hi at +32.
__global__ __launch_bounds__(BLK) void chamfer_fmt(
    const float* __restrict__ pred, const float* __restrict__ gt,
    uint4* __restrict__ fmt, unsigned int* __restrict__ counter) {
  const int gid = blockIdx.x * BLK + threadIdx.x;   // [0, TOTAL_A)
  if (gid == 0) *counter = 0u;                      // reset for pass2fin
  const int arr = gid >> 16;                        // 0=pred, 1=gt
  const int idx = gid & 65535;
  const float* src = arr ? gt : pred;
  float X = src[(size_t)idx * 3 + 0];
  float Y = src[(size_t)idx * 3 + 1];
  float Z = src[(size_t)idx * 3 + 2];
  uint4 lo, hi;
  fmt_point(X, Y, Z, &lo, &hi);
  const int region = gid >> 13;
  const int p      = gid & 8191;
  size_t base = (size_t)region * 16384 + (size_t)(p >> 5) * 64 + (p & 31);
  fmt[base]      = lo;
  fmt[base + 32] = hi;
}

// stage one 4KB chunk (256 uint4): 1 global_load_lds per wave
// (64 lanes x 16B, linear order = the DMA's wave-uniform-base + lane*16).
static __device__ __forceinline__ void stage_chunk(const uint4* src,
                                                   uint4* dst,
                                                   int wave, int lane) {
  const uint4* g = src + wave * 64 + lane;
  uint4*       l = dst + wave * 64;
  __builtin_amdgcn_global_load_lds((gptr_t*)g, (lptr_t*)l, 16, 0, 0);
}

__global__ __launch_bounds__(BLK, 4) void chamfer_mfma_pass1(
    const float* __restrict__ pred, const float* __restrict__ gt,
    const uint4* __restrict__ fmt, float* __restrict__ partial) {
  __shared__ uint4 lds4[NBUF * CU4];   // 4-deep ring, 16KB total

  // bijective XCD swizzle (2048 = 8 * 256)
  const int swz   = ((blockIdx.x & 7) << 8) | (blockIdx.x >> 3);
  const int qc    = swz & 3;           // b-quarter
  const int r     = swz >> 2;
  const int ablk  = r & (ABLKS - 1);
  const int bd    = r >> 5;            // side*8 + batch
  const int batch = bd & 7;
  const int side  = bd >> 3;

  const float* A    = side ? gt : pred;
  const uint4* fmtB = fmt + (size_t)((1 - side) * 8 + batch) * 16384
                          + (size_t)qc * 4096;   // chunk c at + c*CU4

  const int t    = threadIdx.x;
  const int lane = t & 63;
  const int wave = t >> 6;
  const int col  = lane & 31;
  const int hi   = lane >> 5;

  // proven 2-chain shape: 2 named a-frags / 2 named accumulators
  const float* Ab = A + ((size_t)batch * NPTS + (size_t)ablk * 256 + (size_t)wave * 64) * 3;
  f16x8 af0 = make_afrag(Ab[col * 3 + 0], Ab[col * 3 + 1], Ab[col * 3 + 2], hi);
  f16x8 af1 = make_afrag(Ab[(32 + col) * 3 + 0], Ab[(32 + col) * 3 + 1],
                         Ab[(32 + col) * 3 + 2], hi);
  float mq0 = -3.0e38f, mq1 = -3.0e38f;
  const f32x16 zero = {};

  // prologue: DMA chunks 0 and 1 into ring slots 0 and 1
  stage_chunk(fmtB,       lds4,       wave, lane);
  stage_chunk(fmtB + CU4, lds4 + CU4, wave, lane);

  for (int c = 0; c < NCHUNK; ++c) {
    // issue chunk c+2 into ring slot (c+2)&3 (last read at iter c-2;
    // all waves passed >=2 barriers since -> safe)
    if (c + 2 < NCHUNK)
      stage_chunk(fmtB + (size_t)(c + 2) * CU4,
                  lds4 + ((c + 2) & 3) * CU4, wave, lane);

    // counted wait: my chunk-c DMA complete; c+1 (and c+2) stay in
    // flight across the barrier. Tail drains 1 -> 0.
    if (c + 2 < NCHUNK)      asm volatile("s_waitcnt vmcnt(2)" ::: "memory");
    else if (c + 1 < NCHUNK) asm volatile("s_waitcnt vmcnt(1)" ::: "memory");
    else                     asm volatile("s_waitcnt vmcnt(0)" ::: "memory");
    __builtin_amdgcn_s_barrier();          // all waves' chunk-c DMA done
    __builtin_amdgcn_sched_barrier(0);     // pin ds_reads below (rule 18)

    const uint4* rbuf = lds4 + (c & 3) * CU4;
#pragma unroll
    for (int tt = 0; tt < TPC; ++tt) {
      f16x8 bf = *(const f16x8*)(rbuf + tt * 64 + lane);
      f32x16 d0 = mfma_v(bf, af0, zero);
      f32x16 d1 = mfma_v(bf, af1, zero);
      mq0 = fold16(mq0, d0);
      mq1 = fold16(mq1, d1);
    }
  }

  // lanes l, l+32: disjoint b-rows of the same a-col
  mq0 = fmaxf(mq0, __shfl_xor(mq0, 32));
  mq1 = fmaxf(mq1, __shfl_xor(mq1, 32));

  if (lane < 32) {
    size_t a0 = (size_t)bd * NPTS + (size_t)ablk * 256 + (size_t)wave * 64 + col;
    partial[a0 * NCH4 + qc]        = mq0;
    partial[(a0 + 32) * NCH4 + qc] = mq1;
  }
}

__global__ __launch_bounds__(BLK) void chamfer_pass2fin(
    const float4* __restrict__ partial, float* __restrict__ blockSums,
    unsigned int* __restrict__ counter, float* __restrict__ out) {
  __shared__ float wsum[BLK / 64];
  __shared__ int amLast;

  const int gid = blockIdx.x * BLK + threadIdx.x;   // [0, TOTAL_A)
  float4 p = partial[gid];
  float m  = fmaxf(fmaxf(p.x, p.y), fmaxf(p.z, p.w));
  // v = -d2_scaled/2, scale = 256  =>  d2 = m * (-1/128), clamp 0
  float d2 = fmaxf(m * (-1.0f / 128.0f), 0.0f);

  const int lane = threadIdx.x & 63, wave = threadIdx.x >> 6;
  float v = d2;
  for (int off = 32; off > 0; off >>= 1) v += __shfl_down(v, off);
  if (lane == 0) wsum[wave] = v;
  __syncthreads();
  if (threadIdx.x == 0) {
    float s = (wsum[0] + wsum[1]) + (wsum[2] + wsum[3]);
    blockSums[blockIdx.x] = s;
    __threadfence();
    unsigned int prev = atomicAdd(counter, 1u);
    amLast = (prev == P2_BLOCKS - 1);
  }
  __syncthreads();

  // deterministic final reduce by the last block
  if (amLast) {
    __threadfence();
    const volatile float* vbs = blockSums;
    float v2 = vbs[threadIdx.x] + vbs[threadIdx.x + 256];
    for (int off = 32; off > 0; off >>= 1) v2 += __shfl_down(v2, off);
    if (lane == 0) wsum[wave] = v2;
    __syncthreads();
    if (threadIdx.x == 0) {
      float s = ((wsum[0] + wsum[1]) + wsum[2]) + wsum[3];
      out[0] = s * (1.0f / (float)TOTAL_A);   // (sum1+sum2)/(2*65536)
    }
  }
}

extern "C" void kernel_launch(void* const* d_in, const int* in_sizes, int n_in,
                              void* d_out, int out_size, void* d_ws, size_t ws_size,
                              hipStream_t stream) {
  const float* pred = (const float*)d_in[0];
  const float* gt   = (const float*)d_in[1];
  float* out = (float*)d_out;

  uint4*        fmtb      = (uint4*)d_ws;                                  // 4 MB
  float*        partial   = (float*)((char*)d_ws + (size_t)TOTAL_A * 32);  // 2 MB
  float*        blockSums = partial + (size_t)TOTAL_A * NCH4;
  unsigned int* counter   = (unsigned int*)(blockSums + P2_BLOCKS);

  chamfer_fmt<<<TOTAL_A / BLK, BLK, 0, stream>>>(pred, gt, fmtb, counter);
  chamfer_mfma_pass1<<<P1_BLOCKS, BLK, 0, stream>>>(pred, gt, fmtb, partial);
  chamfer_pass2fin<<<P2_BLOCKS, BLK, 0, stream>>>((const float4*)partial,
                                                  blockSums, counter, out);
}